// Round 15
// baseline (169.139 us; speedup 1.0000x reference)
//
#include <hip/hip_runtime.h>
#include <type_traits>

#define NUM_CATEGORIES 64
#define IN_DIM 1024
#define OUT_DIM 1024
#define BATCH 32
#define SEQ 512

#define BM 256
#define BN 256
#define BK 64
#define NT (IN_DIM / BK)   // 16 K-tiles

#define LDA 72     // bf16 elems per A row (128B data + 16B pad) -> 144B stride
#define LDBW 260   // u32 words per B k-pair row (256 data + 4 pad)

typedef float f32x4 __attribute__((ext_vector_type(4)));
typedef float f32x2 __attribute__((ext_vector_type(2)));
typedef unsigned int u32x4 __attribute__((ext_vector_type(4)));
typedef __bf16 bf16x2 __attribute__((ext_vector_type(2)));
typedef __bf16 bf16x4 __attribute__((ext_vector_type(4)));
typedef __bf16 bf16x8 __attribute__((ext_vector_type(8)));

// launch_bounds(512, 1): empirically hipcc maps (512,2) to a 128-VGPR cap
// (R4/R10/R14 all showed 120-128 + spills when structure needed more).
// 138KB LDS already forces 1 block/CU, so (512,1) costs nothing and restores
// the 256-reg budget the 8-phase structure needs (R14 spilled: 273MB scratch).
__global__ __launch_bounds__(512, 1)
void cslinear_kernel(const float* __restrict__ x,
                     const int* __restrict__ cid,
                     const float* __restrict__ weight,
                     const float* __restrict__ bias,
                     float* __restrict__ out) {
    __shared__ unsigned short As[2][BM * LDA];          // 2 x 36 KB
    __shared__ unsigned int   Bs[2][(BK / 2) * LDBW];   // 2 x 32.5 KB (138.5 KB total)

    const int t    = threadIdx.x;
    const int lane = t & 63;
    const int w    = t >> 6;      // 0..7

    // XCD-aware remap: slot s -> XCD s%8; each XCD owns 4 whole batches.
    const int s    = blockIdx.x;      // 0..255
    const int xcd  = s & 7;
    const int ixd  = s >> 3;          // 0..31
    const int b    = xcd + 8 * (ixd >> 3);
    const int j    = ixd & 7;
    const int nt   = j & 3;           // 0..3
    const int mt   = j >> 2;          // 0..1

    const int c = cid[b];
    const float* Wp = weight + (size_t)c * IN_DIM * OUT_DIM + (size_t)nt * BN;
    const float* Xp = x + ((size_t)b * SEQ + (size_t)mt * BM) * IN_DIM;
    float* Op = out + ((size_t)b * SEQ + (size_t)mt * BM) * OUT_DIM + (size_t)nt * BN;

    f32x4 acc[8][4] = {};               // wave tile 128(m) x 64(n)

    const int mbase = (w >> 2) * 128;
    const int nbase = (w & 3) * 64;
    const int lrow  = lane & 15;
    const int lhi   = lane >> 4;

    // 1-deep staging regs (all call-site indices compile-time — rule #20)
    f32x4 ra[8];                        // A: 256x64 f32 / 512 thr
    f32x4 rb0[4], rb1[4];               // B: 64x256 f32 / 512 thr

    auto LOAD_A = [&](int ks) {
        const float* Xk = Xp + ks * BK;
        #pragma unroll
        for (int i = 0; i < 8; ++i) {
            int f   = i * 512 + t;
            int row = f >> 4;             // 0..255
            int c4  = f & 15;             // 0..15
            ra[i] = *reinterpret_cast<const f32x4*>(Xk + (size_t)row * IN_DIM + c4 * 4);
        }
    };
    auto LOAD_B = [&](int ks) {
        const float* Wk = Wp + (size_t)(ks * BK) * OUT_DIM;
        #pragma unroll
        for (int i = 0; i < 4; ++i) {
            int u  = i * 512 + t;
            int kp = u >> 6;              // 0..31
            int n4 = u & 63;              // 0..63
            const float* bse = Wk + (size_t)(2 * kp) * OUT_DIM + n4 * 4;
            rb0[i] = *reinterpret_cast<const f32x4*>(bse);
            rb1[i] = *reinterpret_cast<const f32x4*>(bse + OUT_DIM);
        }
    };

    // single staging pieces (i is a literal at every call site)
    auto ST_A1 = [&](unsigned short* Abuf, int i) {
        char* AsB = reinterpret_cast<char*>(Abuf);
        int f   = i * 512 + t;
        int row = f >> 4;
        int c4  = f & 15;
        bf16x4 a4 = __builtin_convertvector(ra[i], bf16x4);
        *reinterpret_cast<bf16x4*>(AsB + row * (LDA * 2) + c4 * 8) = a4;
    };
    auto ST_B1 = [&](unsigned int* Bbuf, int i) {
        int u  = i * 512 + t;
        int kp = u >> 6;
        int n4 = u & 63;
        u32x4 q;
        #pragma unroll
        for (int jj = 0; jj < 4; ++jj) {
            f32x2 pr;
            pr.x = rb0[i][jj];
            pr.y = rb1[i][jj];
            bf16x2 pb = __builtin_convertvector(pr, bf16x2);
            q[jj] = __builtin_bit_cast(unsigned int, pb);
        }
        *reinterpret_cast<u32x4*>(Bbuf + kp * LDBW + n4 * 4) = q;
    };

    auto RD_B = [&](const unsigned int* Bbuf, int kk, bf16x8* bfr) {
        #pragma unroll
        for (int ni = 0; ni < 4; ++ni) {
            int n   = nbase + ni * 16 + lrow;
            int kp0 = kk * 16 + lhi * 4;
            u32x4 wds;
            #pragma unroll
            for (int jj = 0; jj < 4; ++jj)
                wds[jj] = Bbuf[(kp0 + jj) * LDBW + n];
            bfr[ni] = __builtin_bit_cast(bf16x8, wds);
        }
    };
    auto RD_A = [&](const unsigned short* Abuf, int mih, int kk, bf16x8* afr) {
        const char* AsB = reinterpret_cast<const char*>(Abuf);
        #pragma unroll
        for (int m2 = 0; m2 < 4; ++m2) {
            int r = mbase + (mih * 4 + m2) * 16 + lrow;
            afr[m2] = *reinterpret_cast<const bf16x8*>(AsB + r * (LDA * 2) + kk * 64 + lhi * 16);
        }
    };
    // 16-MFMA quadrant, setprio-wrapped (T5; mih compile-time for acc indexing)
    auto QUAD = [&](auto MIH, const bf16x8* afr, const bf16x8* bfr) {
        constexpr int mih = decltype(MIH)::value;
        __builtin_amdgcn_s_setprio(1);
        #pragma unroll
        for (int m2 = 0; m2 < 4; ++m2) {
            #pragma unroll
            for (int ni = 0; ni < 4; ++ni)
                acc[mih * 4 + m2][ni] = __builtin_amdgcn_mfma_f32_16x16x32_bf16(
                    afr[m2], bfr[ni], acc[mih * 4 + m2][ni], 0, 0, 0);
        }
        __builtin_amdgcn_s_setprio(0);
    };

    constexpr std::integral_constant<int, 0> M0{};
    constexpr std::integral_constant<int, 1> M1{};
    constexpr std::integral_constant<int, 0> S0{};
    constexpr std::integral_constant<int, 1> S1{};

    auto FENCE = [&]() {   // m201 pattern: barrier, lgkm drain, pin (rule #18)
        __builtin_amdgcn_s_barrier();
        asm volatile("s_waitcnt lgkmcnt(0)" ::: "memory");
        __builtin_amdgcn_sched_barrier(0);
    };

    // One K-tile = 4 phases; each phase: {ds_read quadrant frags || staging
    // writes || load-issue} -> barrier -> lgkm(0) -> 16 MFMA -> barrier.
    // Barriers never drain vmcnt (loads stay in flight across them — T4).
    auto KTILE = [&](auto Sr, auto DoStore, auto DoLoad, int tload) {
        constexpr int sr = decltype(Sr)::value;
        constexpr bool do_store = decltype(DoStore)::value;
        constexpr bool do_load  = decltype(DoLoad)::value;
        const unsigned short* Ab = &As[sr][0];
        const unsigned int*   Bb = &Bs[sr][0];
        unsigned short* Aw = &As[sr ^ 1][0];
        unsigned int*   Bw = &Bs[sr ^ 1][0];
        bf16x8 bfr[4], afr[4];

        // P0: kk0 B-frags + A mi0-3; stage A pieces 0-3
        RD_B(Bb, 0, bfr);
        RD_A(Ab, 0, 0, afr);
        if (do_store) { ST_A1(Aw, 0); ST_A1(Aw, 1); ST_A1(Aw, 2); ST_A1(Aw, 3); }
        FENCE();
        QUAD(M0, afr, bfr);
        __builtin_amdgcn_s_barrier();

        // P1: A mi4-7 kk0; stage A pieces 4-7; issue A-loads (regs now free)
        RD_A(Ab, 1, 0, afr);
        if (do_store) { ST_A1(Aw, 4); ST_A1(Aw, 5); ST_A1(Aw, 6); ST_A1(Aw, 7); }
        if (do_load)  LOAD_A(tload);
        FENCE();
        QUAD(M1, afr, bfr);
        __builtin_amdgcn_s_barrier();

        // P2: kk1 B-frags + A mi0-3; stage B pieces 0-1
        RD_B(Bb, 1, bfr);
        RD_A(Ab, 0, 1, afr);
        if (do_store) { ST_B1(Bw, 0); ST_B1(Bw, 1); }
        FENCE();
        QUAD(M0, afr, bfr);
        __builtin_amdgcn_s_barrier();

        // P3: A mi4-7 kk1; stage B pieces 2-3; issue B-loads
        RD_A(Ab, 1, 1, afr);
        if (do_store) { ST_B1(Bw, 2); ST_B1(Bw, 3); }
        if (do_load)  LOAD_B(tload);
        FENCE();
        QUAD(M1, afr, bfr);
        __builtin_amdgcn_s_barrier();
    };

    constexpr std::integral_constant<bool, true>  T{};
    constexpr std::integral_constant<bool, false> F{};

    // prologue: tile0 -> buf0 (latency exposed once); tile1 loads in flight
    LOAD_A(0); LOAD_B(0);
    ST_A1(&As[0][0], 0); ST_A1(&As[0][0], 1); ST_A1(&As[0][0], 2); ST_A1(&As[0][0], 3);
    ST_A1(&As[0][0], 4); ST_A1(&As[0][0], 5); ST_A1(&As[0][0], 6); ST_A1(&As[0][0], 7);
    ST_B1(&Bs[0][0], 0); ST_B1(&Bs[0][0], 1); ST_B1(&Bs[0][0], 2); ST_B1(&Bs[0][0], 3);
    LOAD_A(1); LOAD_B(1);
    asm volatile("s_waitcnt lgkmcnt(0)" ::: "memory");
    __builtin_amdgcn_s_barrier();

    // tiles 0..13: store tile t+1 and load tile t+2 (all flags constant-true)
    for (int tt = 0; tt < NT - 2; tt += 2) {
        KTILE(S0, T, T, tt + 2);
        KTILE(S1, T, T, tt + 3);
    }
    // tail: tile 14 stores tile 15 (no loads); tile 15 pure compute
    KTILE(S0, T, F, 0);
    KTILE(S1, F, F, 0);

    // epilogue: C/D layout col=lane&15, row=(lane>>4)*4+reg
    const int lcol  = lane & 15;
    const int lrow4 = (lane >> 4) * 4;
    float bv[4];
    #pragma unroll
    for (int ni = 0; ni < 4; ++ni)
        bv[ni] = bias[(size_t)c * OUT_DIM + nt * BN + nbase + ni * 16 + lcol];

    #pragma unroll
    for (int mi = 0; mi < 8; ++mi) {
        int rbase = mbase + mi * 16 + lrow4;
        #pragma unroll
        for (int ni = 0; ni < 4; ++ni) {
            int ncol = nbase + ni * 16 + lcol;
            #pragma unroll
            for (int r = 0; r < 4; ++r) {
                Op[(size_t)(rbase + r) * OUT_DIM + ncol] = acc[mi][ni][r] + bv[ni];
            }
        }
    }
}

extern "C" void kernel_launch(void* const* d_in, const int* in_sizes, int n_in,
                              void* d_out, int out_size, void* d_ws, size_t ws_size,
                              hipStream_t stream) {
    const float* x      = (const float*)d_in[0];
    const int*   cid    = (const int*)d_in[1];
    const float* weight = (const float*)d_in[2];
    const float* bias   = (const float*)d_in[3];
    float* out = (float*)d_out;

    dim3 grid(256);     // flat: XCD-aware remap inside kernel; 1 block/CU
    dim3 block(512);
    hipLaunchKernelGGL(cslinear_kernel, grid, block, 0, stream,
                       x, cid, weight, bias, out);
}

// Round 16
// 77.064 us; speedup vs baseline: 2.1948x; 2.1948x over previous
//
#include <hip/hip_runtime.h>
#include <type_traits>

#define NUM_CATEGORIES 64
#define IN_DIM 1024
#define OUT_DIM 1024
#define BATCH 32
#define SEQ 512

#define BM 256
#define BN 256
#define BK 32
#define NSTEP (IN_DIM / BK)   // 32

#define LDA 40     // bf16 elems per A row (64B data + 16B pad)
#define LDBW 260   // u32 words per B k-pair row (256 data + 4 pad)

typedef float f32x4 __attribute__((ext_vector_type(4)));
typedef float f32x2 __attribute__((ext_vector_type(2)));
typedef unsigned int u32x4 __attribute__((ext_vector_type(4)));
typedef __bf16 bf16x2 __attribute__((ext_vector_type(2)));
typedef __bf16 bf16x4 __attribute__((ext_vector_type(4)));
typedef __bf16 bf16x8 __attribute__((ext_vector_type(8)));

// 512-thread block => 8 waves co-resident => <=256 regs/wave incl 128-reg acc
// => hard 128 arch-VGPR budget. This BK=32 phase-split fits it (staging 48 +
// frags 16); the BK=64 variant (R14/R15) could not and spilled.
__global__ __launch_bounds__(512, 2)
void cslinear_kernel(const float* __restrict__ x,
                     const int* __restrict__ cid,
                     const float* __restrict__ weight,
                     const float* __restrict__ bias,
                     float* __restrict__ out) {
    __shared__ unsigned short As[2][BM * LDA];          // 2 x 20 KB
    __shared__ unsigned int   Bs[2][(BK / 2) * LDBW];   // 2 x 16.25 KB

    const int t    = threadIdx.x;
    const int lane = t & 63;
    const int w    = t >> 6;      // 0..7

    // XCD-aware remap: slot s -> XCD s%8; each XCD owns 4 whole batches.
    const int s    = blockIdx.x;      // 0..255
    const int xcd  = s & 7;
    const int ixd  = s >> 3;          // 0..31
    const int b    = xcd + 8 * (ixd >> 3);
    const int j    = ixd & 7;
    const int nt   = j & 3;           // 0..3
    const int mt   = j >> 2;          // 0..1

    const int c = cid[b];
    const float* Wp = weight + (size_t)c * IN_DIM * OUT_DIM + (size_t)nt * BN;
    const float* Xp = x + ((size_t)b * SEQ + (size_t)mt * BM) * IN_DIM;
    float* Op = out + ((size_t)b * SEQ + (size_t)mt * BM) * OUT_DIM + (size_t)nt * BN;

    f32x4 acc[8][4] = {};               // wave tile 128(m) x 64(n) -> AGPRs

    const int mbase = (w >> 2) * 128;
    const int nbase = (w & 3) * 64;
    const int lrow  = lane & 15;
    const int lhi   = lane >> 4;

    // 2-deep staging sets, ALL indices compile-time (rule #20)
    f32x4 ra[2][4];
    f32x4 rb0[2][2], rb1[2][2];

    auto LOAD_A = [&](int ks, auto S) {
        constexpr int ss = decltype(S)::value;
        const float* Xk = Xp + ks * BK;
        #pragma unroll
        for (int i = 0; i < 4; ++i) {
            int f   = i * 512 + t;
            int row = f >> 3;
            int c4  = f & 7;
            ra[ss][i] = *reinterpret_cast<const f32x4*>(Xk + (size_t)row * IN_DIM + c4 * 4);
        }
    };
    auto LOAD_B = [&](int ks, auto S) {
        constexpr int ss = decltype(S)::value;
        const float* Wk = Wp + (size_t)(ks * BK) * OUT_DIM;
        #pragma unroll
        for (int i = 0; i < 2; ++i) {
            int u  = i * 512 + t;
            int kp = u >> 6;
            int n4 = u & 63;
            const float* bse = Wk + (size_t)(2 * kp) * OUT_DIM + n4 * 4;
            rb0[ss][i] = *reinterpret_cast<const f32x4*>(bse);
            rb1[ss][i] = *reinterpret_cast<const f32x4*>(bse + OUT_DIM);
        }
    };

    // single staging pieces (compile-time piece index)
    auto ST_A1 = [&](auto S, auto I) {
        constexpr int ss = decltype(S)::value;
        constexpr int i  = decltype(I)::value;
        char* AsB = reinterpret_cast<char*>(&As[ss][0]);
        int f   = i * 512 + t;
        int row = f >> 3;
        int c4  = f & 7;
        bf16x4 a4 = __builtin_convertvector(ra[ss][i], bf16x4);
        *reinterpret_cast<bf16x4*>(AsB + row * (LDA * 2) + c4 * 8) = a4;
    };
    auto ST_B1 = [&](auto S, auto I) {
        constexpr int ss = decltype(S)::value;
        constexpr int i  = decltype(I)::value;
        unsigned int* BsW = &Bs[ss][0];
        int u  = i * 512 + t;
        int kp = u >> 6;
        int n4 = u & 63;
        u32x4 q;
        #pragma unroll
        for (int jj = 0; jj < 4; ++jj) {
            f32x2 pr;
            pr.x = rb0[ss][i][jj];
            pr.y = rb1[ss][i][jj];
            bf16x2 pb = __builtin_convertvector(pr, bf16x2);
            q[jj] = __builtin_bit_cast(unsigned int, pb);
        }
        *reinterpret_cast<u32x4*>(BsW + kp * LDBW + n4 * 4) = q;
    };

    auto RD_B = [&](auto S, bf16x8* bfr) {
        constexpr int ss = decltype(S)::value;
        const unsigned int* BsW = &Bs[ss][0];
        #pragma unroll
        for (int ni = 0; ni < 4; ++ni) {
            int n   = nbase + ni * 16 + lrow;
            int kp0 = lhi * 4;
            u32x4 wds;
            #pragma unroll
            for (int jj = 0; jj < 4; ++jj)
                wds[jj] = BsW[(kp0 + jj) * LDBW + n];
            bfr[ni] = __builtin_bit_cast(bf16x8, wds);
        }
    };
    auto RD_A = [&](auto S, int mih, bf16x8* afr) {
        constexpr int ss = decltype(S)::value;
        const char* AsB = reinterpret_cast<const char*>(&As[ss][0]);
        #pragma unroll
        for (int m2 = 0; m2 < 4; ++m2) {
            int r = mbase + (mih * 4 + m2) * 16 + lrow;
            afr[m2] = *reinterpret_cast<const bf16x8*>(AsB + r * (LDA * 2) + lhi * 16);
        }
    };
    // 16-MFMA half (mih compile-time for static acc indexing), setprio (T5)
    auto QUAD = [&](auto MIH, const bf16x8* afr, const bf16x8* bfr) {
        constexpr int mih = decltype(MIH)::value;
        __builtin_amdgcn_s_setprio(1);
        #pragma unroll
        for (int m2 = 0; m2 < 4; ++m2) {
            #pragma unroll
            for (int ni = 0; ni < 4; ++ni)
                acc[mih * 4 + m2][ni] = __builtin_amdgcn_mfma_f32_16x16x32_bf16(
                    afr[m2], bfr[ni], acc[mih * 4 + m2][ni], 0, 0, 0);
        }
        __builtin_amdgcn_s_setprio(0);
    };

    constexpr std::integral_constant<int, 0> I0{};
    constexpr std::integral_constant<int, 1> I1{};
    constexpr std::integral_constant<int, 2> I2{};
    constexpr std::integral_constant<int, 3> I3{};
    constexpr std::integral_constant<int, 0> M0{};
    constexpr std::integral_constant<int, 1> M1{};
    constexpr std::integral_constant<int, 0> S0{};
    constexpr std::integral_constant<int, 1> S1{};

    auto FENCE = [&]() {   // barrier, lgkm drain, pin (rule #18)
        __builtin_amdgcn_s_barrier();
        asm volatile("s_waitcnt lgkmcnt(0)" ::: "memory");
        __builtin_amdgcn_sched_barrier(0);
    };

    // One K-step (tile ks, set/buf Sc) = 2 fenced phases.
    // P0: {B-frags + A mi0-3 ds_reads || stage A0,A1,B0 (set Sn) || LOAD_A}
    //     -> barrier -> lgkm(0) -> 16 MFMA -> barrier
    // P1: {A mi4-7 || stage A2,A3,B1 || LOAD_B} -> fence -> 16 MFMA -> barrier
    // Barriers never drain vmcnt (T4). Write->read safety: each phase's
    // lgkm(0) drains its reads+writes before the phase-closing barrier.
    auto KSTEP = [&](auto Sc, auto Sn, bool do_store, bool do_load, int ksl) {
        bf16x8 bfr[4], afr[4];

        RD_B(Sc, bfr);
        RD_A(Sc, 0, afr);
        if (do_store) { ST_A1(Sn, I0); ST_A1(Sn, I1); ST_B1(Sn, I0); }
        if (do_load)  LOAD_A(ksl, Sc);
        FENCE();
        QUAD(M0, afr, bfr);
        __builtin_amdgcn_s_barrier();

        RD_A(Sc, 1, afr);
        if (do_store) { ST_A1(Sn, I2); ST_A1(Sn, I3); ST_B1(Sn, I1); }
        if (do_load)  LOAD_B(ksl, Sc);
        FENCE();
        QUAD(M1, afr, bfr);
        __builtin_amdgcn_s_barrier();
    };

    // prologue: tile0 -> buf0; tile1 loads in flight
    LOAD_A(0, S0); LOAD_B(0, S0);
    ST_A1(S0, I0); ST_A1(S0, I1); ST_A1(S0, I2); ST_A1(S0, I3);
    ST_B1(S0, I0); ST_B1(S0, I1);
    LOAD_A(1, S1); LOAD_B(1, S1);
    asm volatile("s_waitcnt lgkmcnt(0)" ::: "memory");
    __builtin_amdgcn_s_barrier();

    for (int ks = 0; ks < NSTEP; ks += 2) {
        // even: compute tile ks (set0), stage tile ks+1 (set1), load ks+2->set0
        KSTEP(S0, S1, true, ks + 2 < NSTEP, ks + 2);
        // odd: compute tile ks+1 (set1), stage ks+2 (set0), load ks+3->set1
        KSTEP(S1, S0, ks + 2 < NSTEP, ks + 3 < NSTEP, ks + 3);
    }

    // epilogue: C/D layout col=lane&15, row=(lane>>4)*4+reg
    const int lcol  = lane & 15;
    const int lrow4 = (lane >> 4) * 4;
    float bv[4];
    #pragma unroll
    for (int ni = 0; ni < 4; ++ni)
        bv[ni] = bias[(size_t)c * OUT_DIM + nt * BN + nbase + ni * 16 + lcol];

    #pragma unroll
    for (int mi = 0; mi < 8; ++mi) {
        int rbase = mbase + mi * 16 + lrow4;
        #pragma unroll
        for (int ni = 0; ni < 4; ++ni) {
            int ncol = nbase + ni * 16 + lcol;
            #pragma unroll
            for (int r = 0; r < 4; ++r) {
                Op[(size_t)(rbase + r) * OUT_DIM + ncol] = acc[mi][ni][r] + bv[ni];
            }
        }
    }
}

extern "C" void kernel_launch(void* const* d_in, const int* in_sizes, int n_in,
                              void* d_out, int out_size, void* d_ws, size_t ws_size,
                              hipStream_t stream) {
    const float* x      = (const float*)d_in[0];
    const int*   cid    = (const int*)d_in[1];
    const float* weight = (const float*)d_in[2];
    const float* bias   = (const float*)d_in[3];
    float* out = (float*)d_out;

    dim3 grid(256);     // flat: XCD-aware remap inside kernel; 1 block/CU
    dim3 block(512);
    hipLaunchKernelGGL(cslinear_kernel, grid, block, 0, stream,
                       x, cid, weight, bias, out);
}

// Round 17
// 49.167 us; speedup vs baseline: 3.4401x; 1.5674x over previous
//
#include <hip/hip_runtime.h>

#define NUM_CATEGORIES 64
#define IN_DIM 1024
#define OUT_DIM 1024
#define BATCH 32
#define SEQ 512

#define BM 256
#define BN 256
#define BK 32
#define NSTEP (IN_DIM / BK)   // 32

#define LDA 40     // bf16 elems per A row: 64B data + 16B pad = 80B stride
#define LDBW 20    // u32 words per B n-row: 16 kp words + 4 pad = 80B stride

typedef float f32x4 __attribute__((ext_vector_type(4)));
typedef float f32x2 __attribute__((ext_vector_type(2)));
typedef unsigned int u32x4 __attribute__((ext_vector_type(4)));
typedef __bf16 bf16x2 __attribute__((ext_vector_type(2)));
typedef __bf16 bf16x4 __attribute__((ext_vector_type(4)));
typedef __bf16 bf16x8 __attribute__((ext_vector_type(8)));

// 1024 threads = 16 waves = 4 waves/SIMD (2x the TLP of all prior variants;
// m114: co-resident waves overlap MFMA/LDS/VMEM pipes fully). Wave-tile 64x64
// -> acc 64 regs -> ~90 arch VGPR, fits the 128-reg budget of 4-wave/SIMD.
// B LDS is n-major (80B rows): one ds_read_b128 per B-frag (vs 4x b32), and
// stride-80 b128 ops hit all 32 banks uniformly (conflict-free).
__global__ __launch_bounds__(1024, 1)
void cslinear_kernel(const float* __restrict__ x,
                     const int* __restrict__ cid,
                     const float* __restrict__ weight,
                     const float* __restrict__ bias,
                     float* __restrict__ out) {
    __shared__ unsigned short As[2][BM * LDA];   // 2 x 20 KB  [m][k] bf16
    __shared__ unsigned int   Bs[2][BN * LDBW];  // 2 x 20 KB  [n][kp] u32 k-pair words

    const int t    = threadIdx.x;
    const int lane = t & 63;
    const int w    = t >> 6;      // 0..15

    // XCD-aware remap: slot s -> XCD s%8; each XCD owns 4 whole batches.
    const int s    = blockIdx.x;      // 0..255
    const int xcd  = s & 7;
    const int ixd  = s >> 3;          // 0..31
    const int b    = xcd + 8 * (ixd >> 3);
    const int j    = ixd & 7;
    const int nt   = j & 3;           // 0..3
    const int mt   = j >> 2;          // 0..1

    const int c = cid[b];
    const float* Wp = weight + (size_t)c * IN_DIM * OUT_DIM + (size_t)nt * BN;
    const float* Xp = x + ((size_t)b * SEQ + (size_t)mt * BM) * IN_DIM;
    float* Op = out + ((size_t)b * SEQ + (size_t)mt * BM) * OUT_DIM + (size_t)nt * BN;

    f32x4 acc[4][4] = {};               // wave tile 64(m) x 64(n)

    const int mbase = (w >> 2) * 64;    // 0,64,128,192
    const int nbase = (w & 3) * 64;     // 0,64,128,192
    const int lrow  = lane & 15;
    const int lhi   = lane >> 4;        // 0..3

    // 1-deep staging regs (R5 pattern: refilled right after STORET consumes)
    f32x4 ra[2];                        // A: 256x32 f32 / 1024 thr = 2 f32x4
    float rbf[8];                       // B: one 8-deep k-column of one n

    const int an_row = t >> 3;          // A unit 0: row (t + i*1024)>>3
    const int an_c4  = t & 7;
    const int bn_n   = t & 255;         // B: this thread's n-column
    const int bn_kq  = t >> 8;          // 0..3: k-quarter (8 k-rows)

    auto LOADT = [&](int ks) {
        const float* Xk = Xp + ks * BK;
        #pragma unroll
        for (int i = 0; i < 2; ++i) {
            int f   = i * 1024 + t;
            int row = f >> 3;           // 0..255
            int c4  = f & 7;            // 0..7
            ra[i] = *reinterpret_cast<const f32x4*>(Xk + (size_t)row * IN_DIM + c4 * 4);
        }
        const float* Wk = Wp + (size_t)(ks * BK + bn_kq * 8) * OUT_DIM + bn_n;
        #pragma unroll
        for (int e = 0; e < 8; ++e)
            rbf[e] = Wk[(size_t)e * OUT_DIM];   // lanes: consecutive n -> coalesced
    };

    auto STORET = [&](int p) {
        char* AsB = reinterpret_cast<char*>(&As[p][0]);
        #pragma unroll
        for (int i = 0; i < 2; ++i) {
            int f   = i * 1024 + t;
            int row = f >> 3;
            int c4  = f & 7;
            bf16x4 a4 = __builtin_convertvector(ra[i], bf16x4);
            *reinterpret_cast<bf16x4*>(AsB + row * (LDA * 2) + c4 * 8) = a4;
        }
        // B: pack 8 k-floats -> 4 k-pair words -> ONE contiguous b128
        u32x4 q;
        #pragma unroll
        for (int jj = 0; jj < 4; ++jj) {
            f32x2 pr;
            pr.x = rbf[2 * jj];         // k even (low 16)
            pr.y = rbf[2 * jj + 1];     // k odd  (high 16)
            bf16x2 pb = __builtin_convertvector(pr, bf16x2);
            q[jj] = __builtin_bit_cast(unsigned int, pb);
        }
        *reinterpret_cast<u32x4*>(&Bs[p][bn_n * LDBW + bn_kq * 4]) = q;
    };

    LOADT(0);

    for (int ks = 0; ks < NSTEP; ++ks) {
        const int p = ks & 1;

        STORET(p);                          // counted vmcnt waits on staged regs
        if (ks + 1 < NSTEP) LOADT(ks + 1);  // refill; flies across barrier+compute

        asm volatile("s_waitcnt lgkmcnt(0)" ::: "memory");
        __builtin_amdgcn_s_barrier();
        __builtin_amdgcn_sched_barrier(0);

        const char* AsB = reinterpret_cast<const char*>(&As[p][0]);
        const unsigned int* BsW = &Bs[p][0];

        // B frags: one b128 each (n-major layout)
        bf16x8 bfr[4];
        #pragma unroll
        for (int ni = 0; ni < 4; ++ni) {
            int n = nbase + ni * 16 + lrow;
            u32x4 wds = *reinterpret_cast<const u32x4*>(BsW + n * LDBW + lhi * 4);
            bfr[ni] = __builtin_bit_cast(bf16x8, wds);
        }
        #pragma unroll
        for (int mi = 0; mi < 4; ++mi) {
            int r = mbase + mi * 16 + lrow;
            bf16x8 afr = *reinterpret_cast<const bf16x8*>(AsB + r * (LDA * 2) + lhi * 16);
            #pragma unroll
            for (int ni = 0; ni < 4; ++ni)
                acc[mi][ni] = __builtin_amdgcn_mfma_f32_16x16x32_bf16(
                    afr, bfr[ni], acc[mi][ni], 0, 0, 0);
        }
        // double buffer + one barrier/step (R5-proven): buf p next written at
        // step ks+2, after barrier ks+1 ordered all step-ks readers past it.
    }

    // epilogue: C/D layout col=lane&15, row=(lane>>4)*4+reg
    const int lcol  = lane & 15;
    const int lrow4 = (lane >> 4) * 4;
    float bv[4];
    #pragma unroll
    for (int ni = 0; ni < 4; ++ni)
        bv[ni] = bias[(size_t)c * OUT_DIM + nt * BN + nbase + ni * 16 + lcol];

    #pragma unroll
    for (int mi = 0; mi < 4; ++mi) {
        int rbase = mbase + mi * 16 + lrow4;
        #pragma unroll
        for (int ni = 0; ni < 4; ++ni) {
            int ncol = nbase + ni * 16 + lcol;
            #pragma unroll
            for (int r = 0; r < 4; ++r) {
                Op[(size_t)(rbase + r) * OUT_DIM + ncol] = acc[mi][ni][r] + bv[ni];
            }
        }
    }
}

extern "C" void kernel_launch(void* const* d_in, const int* in_sizes, int n_in,
                              void* d_out, int out_size, void* d_ws, size_t ws_size,
                              hipStream_t stream) {
    const float* x      = (const float*)d_in[0];
    const int*   cid    = (const int*)d_in[1];
    const float* weight = (const float*)d_in[2];
    const float* bias   = (const float*)d_in[3];
    float* out = (float*)d_out;

    dim3 grid(256);     // flat: XCD-aware remap inside kernel; 1 block/CU
    dim3 block(1024);   // 16 waves = 4 waves/SIMD
    hipLaunchKernelGGL(cslinear_kernel, grid, block, 0, stream,
                       x, cid, weight, bias, out);
}